// Round 4
// baseline (111.054 us; speedup 1.0000x reference)
//
#include <hip/hip_runtime.h>
#include <hip/hip_cooperative_groups.h>

namespace cg = cooperative_groups;

#define MARGIN 0.1f
#define EPSF   1e-12f
#define BB 32
#define NN 2048
#define DD 128
#define PAD 16   // per-b partials stride in floats (64 B apart)

// ws layout: dist[BB*NN] floats | partials[BB*PAD] floats | ticket[1] int
// partials[b*PAD+0] = row_sum, +1 = n_pos, +2 = n_neg (all via device-scope atomics)

__global__ __launch_bounds__(256) void fused_kernel(const float* __restrict__ anchors,
                                                    const float* __restrict__ feats,
                                                    const int* __restrict__ tgt,
                                                    float* __restrict__ dist,
                                                    float* __restrict__ partials,
                                                    int* __restrict__ ticket,
                                                    float* __restrict__ out) {
    __shared__ float sd[NN + 4];
    __shared__ float pd[64];
    __shared__ int   negcnt, posglob, npblk, lastflag;
    __shared__ float sred[4];

    const int chunk = blockIdx.x;   // 0..31
    const int b     = blockIdx.y;   // 0..31
    const int t     = threadIdx.x;
    const int lane  = t & 63;

    // ---- init scratch (poison-proof, every launch) ----
    if (chunk == 0 && b == 0) {
        if (t < BB * 3) atomicExch(&partials[(t / 3) * PAD + (t % 3)], 0.0f);
        if (t == BB * 3) atomicExch(ticket, 0);
    }

    // ---- phase 1: dist for this block's 64 rows ----
    const int g   = t >> 5;
    const int sub = t & 31;
    const float4 a4 = ((const float4*)(anchors + b * DD))[sub];
    float a2 = a4.x*a4.x + a4.y*a4.y + a4.z*a4.z + a4.w*a4.w;
    #pragma unroll
    for (int m = 16; m >= 1; m >>= 1) a2 += __shfl_xor(a2, m);
    const float ra    = sqrtf(a2);
    const float inva  = 1.0f / (ra + EPSF);
    const float s_anc = (ra * inva) * (ra * inva);

    const float* fp = feats + ((size_t)b * NN) * DD;
    #pragma unroll
    for (int it = 0; it < 8; ++it) {
        const int n = chunk * 64 + it * 8 + g;
        const float4 f4 = ((const float4*)(fp + (size_t)n * DD))[sub];
        float ss = f4.x*f4.x + f4.y*f4.y + f4.z*f4.z + f4.w*f4.w;
        float dt = a4.x*f4.x + a4.y*f4.y + a4.z*f4.z + a4.w*f4.w;
        #pragma unroll
        for (int m = 16; m >= 1; m >>= 1) {
            ss += __shfl_xor(ss, m);
            dt += __shfl_xor(dt, m);
        }
        const float rf   = sqrtf(ss);
        const float invf = 1.0f / (rf + EPSF);
        const float sq   = s_anc + (rf*invf)*(rf*invf) - 2.0f * dt * inva * invf;
        const float dd   = sqrtf(fmaxf(sq, 1e-12f));
        if (sub == 0) dist[b * NN + n] = dd;
    }

    cg::this_grid().sync();

    // ---- phase 2: compacted pair loss ----
    const float* db = dist + b * NN;
    const int*   tb = tgt  + b * NN;

    if (t == 0) { negcnt = 0; posglob = 0; }
    __syncthreads();

    #pragma unroll
    for (int k = 0; k < 8; ++k) {
        const int j  = k * 256 + t;
        const float dv = db[j];
        const int   tv = tb[j];
        const bool  neg = (tv == 0);
        const bool  pos = (tv > 0);
        const unsigned long long nm = __ballot(neg);
        const unsigned long long pm = __ballot(pos);
        int base;
        if (lane == 0) {
            base = atomicAdd(&negcnt, __popcll(nm));
            atomicAdd(&posglob, __popcll(pm));
        }
        base = __shfl(base, 0);
        if (neg) {
            const int off = __popcll(nm & ((1ull << lane) - 1));
            sd[base + off] = dv;
        }
    }
    if (t < 64) {
        const int   i   = chunk * 64 + t;
        const float dv  = db[i];
        const bool  pos = (tb[i] > 0);
        const unsigned long long pm = __ballot(pos);
        if (pos) pd[__popcll(pm & ((1ull << t) - 1))] = dv;
        if (t == 0) npblk = __popcll(pm);
    }
    __syncthreads();

    const int nn     = negcnt;
    const int np     = posglob;
    const int npb    = npblk;
    const int nn_pad = (nn + 3) & ~3;
    if (t < nn_pad - nn) sd[nn + t] = 1e30f;   // sentinel pad -> relu 0
    __syncthreads();

    float acc = 0.0f;
    const int p = t >> 2;
    if (p < npb) {
        const float   x  = pd[p] + MARGIN;
        const float4* s4 = (const float4*)sd;
        const int    nf4 = nn_pad >> 2;
        float a0 = 0.f, a1 = 0.f, a2_ = 0.f, a3 = 0.f;
        #pragma unroll 4
        for (int f = (t & 3); f < nf4; f += 4) {
            const float4 q = s4[f];        // 4 distinct addrs/wave -> broadcast, conflict-free
            a0  += fmaxf(x - q.x, 0.0f);
            a1  += fmaxf(x - q.y, 0.0f);
            a2_ += fmaxf(x - q.z, 0.0f);
            a3  += fmaxf(x - q.w, 0.0f);
        }
        acc = (a0 + a1) + (a2_ + a3);
    }

    #pragma unroll
    for (int m = 32; m >= 1; m >>= 1) acc += __shfl_xor(acc, m);
    if (lane == 0) sred[t >> 6] = acc;
    __syncthreads();

    // ---- fan-in finish: last ticketed block computes out[0] ----
    if (t == 0) {
        const float bsum = (sred[0] + sred[1]) + (sred[2] + sred[3]);
        atomicAdd(&partials[b * PAD], bsum);
        if (chunk == 0) {
            atomicExch(&partials[b * PAD + 1], (float)np);
            atomicExch(&partials[b * PAD + 2], (float)nn);
        }
        __threadfence();
        const int tk = atomicAdd(ticket, 1);
        lastflag = (tk == 32 * 32 - 1) ? 1 : 0;
    }
    __syncthreads();

    if (lastflag) {
        float v = 0.0f;
        if (t < BB) {
            const float rs   = atomicAdd(&partials[t * PAD], 0.0f);
            const float npf  = atomicAdd(&partials[t * PAD + 1], 0.0f);
            const float nnf  = atomicAdd(&partials[t * PAD + 2], 0.0f);
            const float den  = fmaxf(npf * nnf, 1.0f);
            v = (npf > 0.0f) ? rs / den : MARGIN;
        }
        if (t < 64) {
            #pragma unroll
            for (int m = 32; m >= 1; m >>= 1) v += __shfl_xor(v, m);
            if (t == 0) out[0] = v;
        }
    }
}

extern "C" void kernel_launch(void* const* d_in, const int* in_sizes, int n_in,
                              void* d_out, int out_size, void* d_ws, size_t ws_size,
                              hipStream_t stream) {
    const float* anchors = (const float*)d_in[0];
    const float* feats   = (const float*)d_in[1];
    const int*   tgt     = (const int*)d_in[2];
    float*       out     = (float*)d_out;

    float* dist     = (float*)d_ws;                    // BB*NN floats
    float* partials = dist + BB * NN;                  // BB*PAD floats
    int*   ticket   = (int*)(partials + BB * PAD);     // 1 int

    void* args[] = { (void*)&anchors, (void*)&feats, (void*)&tgt,
                     (void*)&dist, (void*)&partials, (void*)&ticket, (void*)&out };
    hipLaunchCooperativeKernel((void*)fused_kernel, dim3(32, 32), dim3(256),
                               args, 0, stream);
}

// Round 6
// 40.390 us; speedup vs baseline: 2.7495x; 2.7495x over previous
//
#include <hip/hip_runtime.h>

#define MARGIN 0.1f
#define EPSF   1e-12f
#define BB 32
#define NN 2048
#define DD 128

// ws layout: dist[BB*NN] f32 | partials[BB*32] f32 | cnts[BB*2] f32 | ticket[1] int
// All float accumulation is order-fixed (no float atomics) -> bitwise-deterministic.

// Kernel 1: dist[b][n]. 32-lane group per row, float4 loads. Resets ticket.
__global__ __launch_bounds__(256) void dist_kernel(const float* __restrict__ anchors,
                                                   const float* __restrict__ feats,
                                                   float* __restrict__ dist,
                                                   int* __restrict__ ticket) {
    const int chunk = blockIdx.x;   // 0..31 (64 rows each)
    const int b     = blockIdx.y;   // 0..31
    const int t     = threadIdx.x;
    const int g     = t >> 5;       // group 0..7
    const int sub   = t & 31;       // lane within group

    if (chunk == 0 && b == 0 && t == 0) *ticket = 0;

    const float4 a4 = ((const float4*)(anchors + b * DD))[sub];
    float a2 = a4.x*a4.x + a4.y*a4.y + a4.z*a4.z + a4.w*a4.w;
    #pragma unroll
    for (int m = 16; m >= 1; m >>= 1) a2 += __shfl_xor(a2, m);
    const float ra    = sqrtf(a2);
    const float inva  = 1.0f / (ra + EPSF);
    const float s_anc = (ra * inva) * (ra * inva);

    const float* fp = feats + ((size_t)b * NN) * DD;
    #pragma unroll
    for (int it = 0; it < 8; ++it) {
        const int n = chunk * 64 + it * 8 + g;
        const float4 f4 = ((const float4*)(fp + (size_t)n * DD))[sub];
        float ss = f4.x*f4.x + f4.y*f4.y + f4.z*f4.z + f4.w*f4.w;
        float dt = a4.x*f4.x + a4.y*f4.y + a4.z*f4.z + a4.w*f4.w;
        #pragma unroll
        for (int m = 16; m >= 1; m >>= 1) {
            ss += __shfl_xor(ss, m);
            dt += __shfl_xor(dt, m);
        }
        const float rf   = sqrtf(ss);
        const float invf = 1.0f / (rf + EPSF);
        const float sq   = s_anc + (rf*invf)*(rf*invf) - 2.0f * dt * inva * invf;
        const float dd   = sqrtf(fmaxf(sq, 1e-12f));
        if (sub == 0) dist[b * NN + n] = dd;
    }
}

// Kernel 2: deterministic compacted pair loss + ticket fan-in final.
__global__ __launch_bounds__(256) void pair_kernel(const float* __restrict__ dist,
                                                   const int* __restrict__ tgt,
                                                   float* __restrict__ partials,
                                                   float* __restrict__ cnts,
                                                   int* __restrict__ ticket,
                                                   float* __restrict__ out) {
    __shared__ float sd[NN + 8];
    __shared__ float pd[64];
    __shared__ int   cntk[32], posk[32], pref[33];
    __shared__ int   npos_sh, npblk, lastflag;
    __shared__ float sred[4];

    const int chunk = blockIdx.x;   // 0..31
    const int b     = blockIdx.y;   // 0..31
    const int t     = threadIdx.x;
    const int lane  = t & 63;
    const int w     = t >> 6;       // wave 0..3

    const float* db = dist + b * NN;
    const int*   tb = tgt  + b * NN;

    // Pass 1: flags + per-(k,wave) counts. j = k*256 + w*64 + lane (order q = k*4+w).
    float dvv[8]; bool ngg[8];
    #pragma unroll
    for (int k = 0; k < 8; ++k) {
        const int j  = k * 256 + t;
        dvv[k] = db[j];
        const int tv = tb[j];
        ngg[k] = (tv == 0);
        const bool pos = (tv > 0);
        const unsigned long long nm = __ballot(ngg[k]);
        const unsigned long long pm = __ballot(pos);
        if (lane == 0) { cntk[k * 4 + w] = __popcll(nm); posk[k * 4 + w] = __popcll(pm); }
    }
    __syncthreads();
    if (t == 0) {   // serial exclusive prefix in fixed j-order: deterministic
        int run = 0, pp = 0;
        #pragma unroll
        for (int q = 0; q < 32; ++q) { pref[q] = run; run += cntk[q]; pp += posk[q]; }
        pref[32] = run;
        npos_sh  = pp;
    }
    // Compact this block's positive d_i (wave 0 = threads 0..63, ballot order fixed).
    if (t < 64) {
        const int   i   = chunk * 64 + t;
        const float dv  = db[i];
        const bool  pos = (tb[i] > 0);
        const unsigned long long pm = __ballot(pos);
        if (pos) pd[__popcll(pm & ((1ull << t) - 1))] = dv;
        if (t == 0) npblk = __popcll(pm);
    }
    __syncthreads();

    // Pass 2: scatter negatives at deterministic offsets (sd sorted by j).
    #pragma unroll
    for (int k = 0; k < 8; ++k) {
        const unsigned long long nm = __ballot(ngg[k]);
        if (ngg[k]) {
            const int off = pref[k * 4 + w] + __popcll(nm & ((1ull << lane) - 1));
            sd[off] = dvv[k];
        }
    }
    __syncthreads();

    const int nn     = pref[32];
    const int np     = npos_sh;
    const int npb    = npblk;
    const int nn_pad = (nn + 7) & ~7;
    if (t < nn_pad - nn) sd[nn + t] = 1e30f;   // sentinel pad -> relu 0
    __syncthreads();

    // Octet layout: 8 threads per positive slot, interleaved float4 j-stripes.
    float acc = 0.0f;
    {
        const int     s   = t & 7;
        const float4* s4  = (const float4*)sd;
        const int     nf4 = nn_pad >> 2;
        for (int p = t >> 3; p < npb; p += 32) {
            const float x = pd[p] + MARGIN;
            float a0 = 0.f, a1 = 0.f, a2_ = 0.f, a3 = 0.f;
            #pragma unroll 4
            for (int f = s; f < nf4; f += 8) {
                const float4 q = s4[f];    // 8 distinct addrs/wave -> conflict-free broadcast
                a0  += fmaxf(x - q.x, 0.0f);
                a1  += fmaxf(x - q.y, 0.0f);
                a2_ += fmaxf(x - q.z, 0.0f);
                a3  += fmaxf(x - q.w, 0.0f);
            }
            acc += (a0 + a1) + (a2_ + a3);
        }
    }

    #pragma unroll
    for (int m = 32; m >= 1; m >>= 1) acc += __shfl_xor(acc, m);
    if (lane == 0) sred[w] = acc;
    __syncthreads();

    // Block partial: plain store (no float atomics), then fence + integer ticket.
    if (t == 0) {
        partials[b * 32 + chunk] = (sred[0] + sred[1]) + (sred[2] + sred[3]);
        if (chunk == 0) { cnts[b * 2] = (float)np; cnts[b * 2 + 1] = (float)nn; }
        __threadfence();
        const int tk = atomicAdd(ticket, 1);
        lastflag = (tk == 32 * 32 - 1) ? 1 : 0;
    }
    __syncthreads();

    // Last block: fixed-order reduction over all partials -> out[0].
    if (lastflag) {
        float v = 0.0f;
        if (t < BB) {
            float rs = 0.0f;
            for (int c = 0; c < 32; ++c)
                rs += atomicAdd(&partials[t * 32 + c], 0.0f);   // coherent read, +0 no-op
            const float npf = atomicAdd(&cnts[t * 2], 0.0f);
            const float nnf = atomicAdd(&cnts[t * 2 + 1], 0.0f);
            const float den = fmaxf(npf * nnf, 1.0f);
            v = (npf > 0.0f) ? rs / den : MARGIN;
        }
        if (t < 64) {
            #pragma unroll
            for (int m = 32; m >= 1; m >>= 1) v += __shfl_xor(v, m);
            if (t == 0) out[0] = v;
        }
    }
}

extern "C" void kernel_launch(void* const* d_in, const int* in_sizes, int n_in,
                              void* d_out, int out_size, void* d_ws, size_t ws_size,
                              hipStream_t stream) {
    const float* anchors = (const float*)d_in[0];
    const float* feats   = (const float*)d_in[1];
    const int*   tgt     = (const int*)d_in[2];
    float*       out     = (float*)d_out;

    float* dist     = (float*)d_ws;                 // BB*NN floats
    float* partials = dist + BB * NN;               // BB*32 floats
    float* cnts     = partials + BB * 32;           // BB*2 floats
    int*   ticket   = (int*)(cnts + BB * 2);        // 1 int

    dist_kernel<<<dim3(32, 32), 256, 0, stream>>>(anchors, feats, dist, ticket);
    pair_kernel<<<dim3(32, 32), 256, 0, stream>>>(dist, tgt, partials, cnts, ticket, out);
}

// Round 7
// 29.277 us; speedup vs baseline: 3.7933x; 1.3796x over previous
//
#include <hip/hip_runtime.h>

#define MARGIN 0.1f
#define EPSF   1e-12f
#define BB 32
#define NN 2048
#define DD 128

// ws layout: dist[BB*NN] f32 | partials[BB*2] f32 | cnts[BB*2] f32 | ticket[1] int
// All float accumulation is order-fixed (no float atomics) -> bitwise-deterministic.

// Kernel 1: dist[b][n]. 32-lane group per row, float4 loads. Resets ticket.
__global__ __launch_bounds__(256) void dist_kernel(const float* __restrict__ anchors,
                                                   const float* __restrict__ feats,
                                                   float* __restrict__ dist,
                                                   int* __restrict__ ticket) {
    const int chunk = blockIdx.x;   // 0..31 (64 rows each)
    const int b     = blockIdx.y;   // 0..31
    const int t     = threadIdx.x;
    const int g     = t >> 5;       // group 0..7
    const int sub   = t & 31;       // lane within group

    if (chunk == 0 && b == 0 && t == 0) *ticket = 0;

    const float4 a4 = ((const float4*)(anchors + b * DD))[sub];
    float a2 = a4.x*a4.x + a4.y*a4.y + a4.z*a4.z + a4.w*a4.w;
    #pragma unroll
    for (int m = 16; m >= 1; m >>= 1) a2 += __shfl_xor(a2, m);
    const float ra    = sqrtf(a2);
    const float inva  = 1.0f / (ra + EPSF);
    const float s_anc = (ra * inva) * (ra * inva);

    const float* fp = feats + ((size_t)b * NN) * DD;
    #pragma unroll
    for (int it = 0; it < 8; ++it) {
        const int n = chunk * 64 + it * 8 + g;
        const float4 f4 = ((const float4*)(fp + (size_t)n * DD))[sub];
        float ss = f4.x*f4.x + f4.y*f4.y + f4.z*f4.z + f4.w*f4.w;
        float dt = a4.x*f4.x + a4.y*f4.y + a4.z*f4.z + a4.w*f4.w;
        #pragma unroll
        for (int m = 16; m >= 1; m >>= 1) {
            ss += __shfl_xor(ss, m);
            dt += __shfl_xor(dt, m);
        }
        const float rf   = sqrtf(ss);
        const float invf = 1.0f / (rf + EPSF);
        const float sq   = s_anc + (rf*invf)*(rf*invf) - 2.0f * dt * inva * invf;
        const float dd   = sqrtf(fmaxf(sq, 1e-12f));
        if (sub == 0) dist[b * NN + n] = dd;
    }
}

// Kernel 2: deterministic compacted pair loss, 64 blocks (2 x 32 b) x 1024 thr.
// Small fan-in: 64 fences + 64 ticket atomics, last block writes out[0].
__global__ __launch_bounds__(1024) void pair_kernel(const float* __restrict__ dist,
                                                    const int* __restrict__ tgt,
                                                    float* __restrict__ partials,
                                                    float* __restrict__ cnts,
                                                    int* __restrict__ ticket,
                                                    float* __restrict__ out) {
    __shared__ float sd[NN + 8];
    __shared__ float pd[1024 + 8];
    __shared__ int   cntk[32], posk[32], pref[33];
    __shared__ int   pcnt[16], ppref[17];
    __shared__ int   np_sh, lastflag;
    __shared__ float sred[16];

    const int chunk = blockIdx.x;   // 0..1 (half of the i-rows)
    const int b     = blockIdx.y;   // 0..31
    const int t     = threadIdx.x;  // 0..1023
    const int lane  = t & 63;
    const int w     = t >> 6;       // wave 0..15

    const float* db = dist + b * NN;
    const int*   tb = tgt  + b * NN;

    // Pass 1: full-row flags + per-(k,wave) counts (fixed j-order q = k*16+w).
    float dvv[2]; bool ngg[2];
    #pragma unroll
    for (int k = 0; k < 2; ++k) {
        const int j  = k * 1024 + t;
        dvv[k] = db[j];
        const int tv = tb[j];
        ngg[k] = (tv == 0);
        const bool pos = (tv > 0);
        const unsigned long long nm = __ballot(ngg[k]);
        const unsigned long long pm = __ballot(pos);
        if (lane == 0) { cntk[k * 16 + w] = __popcll(nm); posk[k * 16 + w] = __popcll(pm); }
    }
    // own i-row (one per thread)
    const int   i    = chunk * 1024 + t;
    const float di   = db[i];
    const bool  posi = (tb[i] > 0);
    {
        const unsigned long long pm = __ballot(posi);
        if (lane == 0) pcnt[w] = __popcll(pm);
    }
    __syncthreads();
    if (t == 0) {   // serial exclusive prefixes in fixed order: deterministic
        int run = 0, pp = 0;
        #pragma unroll
        for (int q = 0; q < 32; ++q) { pref[q] = run; run += cntk[q]; pp += posk[q]; }
        pref[32] = run;
        np_sh    = pp;
        int pr = 0;
        #pragma unroll
        for (int q = 0; q < 16; ++q) { ppref[q] = pr; pr += pcnt[q]; }
        ppref[16] = pr;
    }
    __syncthreads();

    // Pass 2: scatter at deterministic offsets (sd sorted by j, pd by i).
    #pragma unroll
    for (int k = 0; k < 2; ++k) {
        const unsigned long long nm = __ballot(ngg[k]);
        if (ngg[k]) sd[pref[k * 16 + w] + __popcll(nm & ((1ull << lane) - 1))] = dvv[k];
    }
    {
        const unsigned long long pm = __ballot(posi);
        if (posi) pd[ppref[w] + __popcll(pm & ((1ull << lane) - 1))] = di;
    }
    __syncthreads();

    const int nn     = pref[32];
    const int np     = np_sh;
    const int npb    = ppref[16];
    const int nn_pad = (nn + 7) & ~7;
    if (t < nn_pad - nn) sd[nn + t] = 1e30f;   // sentinel pad -> relu 0
    __syncthreads();

    // Octet layout: 8 threads per positive slot, interleaved float4 j-stripes.
    float acc = 0.0f;
    {
        const int     s   = t & 7;
        const float4* s4  = (const float4*)sd;
        const int     nf4 = nn_pad >> 2;
        for (int p = t >> 3; p < npb; p += 128) {
            const float x = pd[p] + MARGIN;
            float a0 = 0.f, a1 = 0.f, a2_ = 0.f, a3 = 0.f;
            #pragma unroll 4
            for (int f = s; f < nf4; f += 8) {
                const float4 q = s4[f];    // 8 x 16B lines span 32 banks: 2-way = free
                a0  += fmaxf(x - q.x, 0.0f);
                a1  += fmaxf(x - q.y, 0.0f);
                a2_ += fmaxf(x - q.z, 0.0f);
                a3  += fmaxf(x - q.w, 0.0f);
            }
            acc += (a0 + a1) + (a2_ + a3);
        }
    }

    #pragma unroll
    for (int m = 32; m >= 1; m >>= 1) acc += __shfl_xor(acc, m);
    if (lane == 0) sred[w] = acc;
    __syncthreads();

    // Block partial: plain store, fence, small integer ticket (64 participants).
    if (t == 0) {
        float bsum = 0.0f;
        #pragma unroll
        for (int q = 0; q < 16; ++q) bsum += sred[q];   // fixed order
        partials[b * 2 + chunk] = bsum;
        if (chunk == 0) { cnts[b * 2] = (float)np; cnts[b * 2 + 1] = (float)nn; }
        __threadfence();
        lastflag = (atomicAdd(ticket, 1) == 2 * BB - 1) ? 1 : 0;
    }
    __syncthreads();

    // Last block: fixed-order reduction over all partials -> out[0].
    if (lastflag) {
        float v = 0.0f;
        if (t < BB) {
            const float rs  = atomicAdd(&partials[t * 2], 0.0f)
                            + atomicAdd(&partials[t * 2 + 1], 0.0f);   // coherent reads
            const float npf = atomicAdd(&cnts[t * 2], 0.0f);
            const float nnf = atomicAdd(&cnts[t * 2 + 1], 0.0f);
            const float den = fmaxf(npf * nnf, 1.0f);
            v = (npf > 0.0f) ? rs / den : MARGIN;
        }
        if (t < 64) {
            #pragma unroll
            for (int m = 32; m >= 1; m >>= 1) v += __shfl_xor(v, m);
            if (t == 0) out[0] = v;
        }
    }
}

extern "C" void kernel_launch(void* const* d_in, const int* in_sizes, int n_in,
                              void* d_out, int out_size, void* d_ws, size_t ws_size,
                              hipStream_t stream) {
    const float* anchors = (const float*)d_in[0];
    const float* feats   = (const float*)d_in[1];
    const int*   tgt     = (const int*)d_in[2];
    float*       out     = (float*)d_out;

    float* dist     = (float*)d_ws;                 // BB*NN floats
    float* partials = dist + BB * NN;               // BB*2 floats
    float* cnts     = partials + BB * 2;            // BB*2 floats
    int*   ticket   = (int*)(cnts + BB * 2);        // 1 int

    dist_kernel<<<dim3(32, 32), 256, 0, stream>>>(anchors, feats, dist, ticket);
    pair_kernel<<<dim3(2, 32), 1024, 0, stream>>>(dist, tgt, partials, cnts, ticket, out);
}